// Round 13
// baseline (449.458 us; speedup 1.0000x reference)
//
#include <hip/hip_runtime.h>
#include <hip/hip_bf16.h>

#define MUL_Sc 256
#define DIM_Hc 640
#define IN_COLS 644
#define KF 768
#define NT 32
#define GRIDB 256

#define C0F 0.05103103630798287f
#define INV_SQRT3F 0.57735026918962576f

typedef __attribute__((ext_vector_type(8))) short short8;
typedef __attribute__((ext_vector_type(4))) float f32x4;

#define MFMA(a, b, c) __builtin_amdgcn_mfma_f32_16x16x32_bf16((a), (b), (c), 0, 0, 0)

__device__ __forceinline__ unsigned short f2bf(float x) {
    union { float f; unsigned u; } v; v.f = x;
    unsigned r = v.u + 0x7fffu + ((v.u >> 16) & 1u);   // RNE
    return (unsigned short)(r >> 16);
}

// ---- weight prep: fp32 [k][col] -> bf16 transposed [col][k] (proven numerics) ----
// WT_sg 384x384: cols 0..255 scal (k<256: Wss, k>=256: Wvv), cols 256..383 gate (Wssg/Wvvg)
// WT_sv 128x256, WT_vs 128x128
__global__ void prep_weights(const float* __restrict__ Wss, const float* __restrict__ Wvv,
                             const float* __restrict__ Wssg, const float* __restrict__ Wvvg,
                             const float* __restrict__ Wsv, const float* __restrict__ Wvs,
                             unsigned short* __restrict__ wt) {
    int i = blockIdx.x * 256 + threadIdx.x;
    const int N_SG = 384 * 384;
    const int N_SV = 128 * 256;
    const int N_VS = 128 * 128;
    if (i < N_SG) {
        int col = i / 384, k = i % 384;
        float v;
        if (col < 256) v = (k < 256) ? Wss[k * 256 + col] : Wvv[(k - 256) * 256 + col];
        else { int c = col - 256; v = (k < 256) ? Wssg[k * 128 + c] : Wvvg[(k - 256) * 128 + c]; }
        wt[i] = f2bf(v);
    } else if (i < N_SG + N_SV) {
        int j = i - N_SG; int col = j >> 8, k = j & 255;
        wt[i] = f2bf(Wsv[k * 128 + col]);
    } else if (i < N_SG + N_SV + N_VS) {
        int j = i - N_SG - N_SV; int col = j >> 7, k = j & 127;
        wt[i] = f2bf(Wvs[k * 128 + col]);
    }
}

// ---- persistent fused kernel: dbuf feat + issue-early/convert-late + raw barrier ----
// feat row per node (bf16, 768): [ xs(0:256) | dot(256:384) | xv_k0(384:512) | xv_k1(512:640) | xv_k2(640:768) ]
__global__ __launch_bounds__(512, 2)
void fused_main(const float* __restrict__ din, const unsigned short* __restrict__ wt,
                const float* __restrict__ bias, float* __restrict__ out,
                int N, int ntiles) {
    __shared__ unsigned short feat[2][NT * KF];   // 2 x 48 KB
    __shared__ float psv[2][NT * 4];

    const int tid = threadIdx.x;
    const int g = tid >> 4;       // staging: local node 0..31
    const int j = tid & 15;       // 16 threads per node

    const int wave = tid >> 6;
    const int lane = tid & 63;
    const int l15  = lane & 15;
    const int lkb  = (lane >> 4) << 3;
    const int rbase = (lane >> 4) << 2;
    const int swzr = (l15 & 7) << 4;

    const unsigned short* WTsg = wt;
    const unsigned short* WTsv = wt + 384 * 384;
    const unsigned short* WTvs = wt + 384 * 384 + 128 * 256;

    // bias per thread (cols fixed across tiles)
    float bc0 = bias[(wave)     * 16 + l15];
    float bc1 = bias[(wave + 8) * 16 + l15];

    // -------- staging registers (held across compute) --------
    float4 xs4[4], xv4[6], pp;

    auto issue = [&](int tile) {
        int n = tile * NT + g; if (n >= N) n = N - 1;
        const float* row = din + (size_t)n * IN_COLS;
        #pragma unroll
        for (int q = 0; q < 4; ++q) xs4[q] = *(const float4*)(row + 16 * j + 4 * q);
        #pragma unroll
        for (int q = 0; q < 6; ++q) xv4[q] = *(const float4*)(row + MUL_Sc + 24 * j + 4 * q);
        pp = *(const float4*)(row + DIM_Hc);
    };

    auto convertw = [&](int wb) {
        char* fb = (char*)&feat[wb][0];
        const int swz  = (g & 7) << 4;
        const int rowb = g * (KF * 2);
        float ps = pp.x, pv0 = pp.y, pv1 = pp.z, pv2 = pp.w;
        (void)ps;
        if (j == 0) {
            psv[wb][g*4+0] = pp.x; psv[wb][g*4+1] = pp.y;
            psv[wb][g*4+2] = pp.z; psv[wb][g*4+3] = pp.w;
        }
        // xs: 16 consecutive elems -> 2x b128 (R5 verbatim math)
        {
            int c = 16 * j;
            float4 x0 = xs4[0], x1 = xs4[1], x2 = xs4[2], x3 = xs4[3];
            short8 p0, p1;
            p0[0]=(short)f2bf(x0.x); p0[1]=(short)f2bf(x0.y); p0[2]=(short)f2bf(x0.z); p0[3]=(short)f2bf(x0.w);
            p0[4]=(short)f2bf(x1.x); p0[5]=(short)f2bf(x1.y); p0[6]=(short)f2bf(x1.z); p0[7]=(short)f2bf(x1.w);
            p1[0]=(short)f2bf(x2.x); p1[1]=(short)f2bf(x2.y); p1[2]=(short)f2bf(x2.z); p1[3]=(short)f2bf(x2.w);
            p1[4]=(short)f2bf(x3.x); p1[5]=(short)f2bf(x3.y); p1[6]=(short)f2bf(x3.z); p1[7]=(short)f2bf(x3.w);
            *(short8*)(fb + ((rowb + c * 2) ^ swz))       = p0;
            *(short8*)(fb + ((rowb + (c + 8) * 2) ^ swz)) = p1;
        }
        // xv: 8 consecutive u -> dot + 3 k-planes (R5 verbatim math)
        {
            int u0 = 8 * j;
            float e[24];
            #pragma unroll
            for (int q = 0; q < 6; ++q) {
                float4 v = xv4[q];
                e[4*q+0] = v.x; e[4*q+1] = v.y; e[4*q+2] = v.z; e[4*q+3] = v.w;
            }
            short8 dp, k0, k1, k2;
            #pragma unroll
            for (int m = 0; m < 8; ++m) {
                float a = e[3*m], b = e[3*m+1], c = e[3*m+2];
                dp[m] = (short)f2bf((a * pv0 + b * pv1 + c * pv2) * INV_SQRT3F);
                k0[m] = (short)f2bf(a);
                k1[m] = (short)f2bf(b);
                k2[m] = (short)f2bf(c);
            }
            *(short8*)(fb + ((rowb + (256 + u0) * 2) ^ swz)) = dp;
            *(short8*)(fb + ((rowb + (384 + u0) * 2) ^ swz)) = k0;
            *(short8*)(fb + ((rowb + (512 + u0) * 2) ^ swz)) = k1;
            *(short8*)(fb + ((rowb + (640 + u0) * 2) ^ swz)) = k2;
        }
    };

    // -------- prologue --------
    const int t0 = blockIdx.x;
    if (t0 < ntiles) { issue(t0); convertw(0); }
    __syncthreads();

    int cur = 0;
    for (int tile = t0; tile < ntiles; tile += GRIDB) {
        const int nx = tile + GRIDB;
        if (nx < ntiles) issue(nx);     // async staging loads for next tile

        // ================= compute tile from feat[cur] (R5-verified mapping) =================
        {
            const char* fbr = (const char*)&feat[cur][0];
            const float* pvv = &psv[cur][0];
            const int n0 = tile * NT;

            float pss[2][4];
            #pragma unroll
            for (int m = 0; m < 2; ++m)
            #pragma unroll
            for (int i = 0; i < 4; ++i) pss[m][i] = pvv[(m * 16 + rbase + i) * 4];

            // ---- sg GEMM: t=0,1 scal col-tiles, t=2 gate col-tile ----
            f32x4 accS[3][2];
            #pragma unroll
            for (int t = 0; t < 3; ++t) { accS[t][0] = (f32x4){0,0,0,0}; accS[t][1] = (f32x4){0,0,0,0}; }

            #pragma unroll
            for (int ks = 0; ks < 8; ++ks) {      // xs part K=256
                int kf = ks * 32 + lkb;
                short8 a0 = *(const short8*)(fbr + ((l15 * 1536 + kf * 2) ^ swzr));
                short8 a1 = *(const short8*)(fbr + (((16 + l15) * 1536 + kf * 2) ^ swzr));
                #pragma unroll
                for (int t = 0; t < 3; ++t) {
                    int ct = wave + t * 8;        // t=2 -> gate cols 256+wave*16
                    short8 b = *(const short8*)(WTsg + (ct * 16 + l15) * 384 + ks * 32 + lkb);
                    accS[t][0] = MFMA(a0, b, accS[t][0]);
                    accS[t][1] = MFMA(a1, b, accS[t][1]);
                }
            }
            #pragma unroll
            for (int t = 0; t < 3; ++t)
            #pragma unroll
            for (int m = 0; m < 2; ++m)
            #pragma unroll
            for (int i = 0; i < 4; ++i) accS[t][m][i] *= pss[m][i];
            #pragma unroll
            for (int ks = 0; ks < 4; ++ks) {      // dot part K=128
                int kf = 256 + ks * 32 + lkb;
                short8 a0 = *(const short8*)(fbr + ((l15 * 1536 + kf * 2) ^ swzr));
                short8 a1 = *(const short8*)(fbr + (((16 + l15) * 1536 + kf * 2) ^ swzr));
                #pragma unroll
                for (int t = 0; t < 3; ++t) {
                    int ct = wave + t * 8;
                    short8 b = *(const short8*)(WTsg + (ct * 16 + l15) * 384 + 256 + ks * 32 + lkb);
                    accS[t][0] = MFMA(a0, b, accS[t][0]);
                    accS[t][1] = MFMA(a1, b, accS[t][1]);
                }
            }

            // scal epilogue: silu -> global
            #pragma unroll
            for (int t = 0; t < 2; ++t) {
                int col = (wave + t * 8) * 16 + l15;
                float bc = t == 0 ? bc0 : bc1;
                #pragma unroll
                for (int m = 0; m < 2; ++m)
                #pragma unroll
                for (int i = 0; i < 4; ++i) {
                    int n = n0 + m * 16 + rbase + i;
                    if (n < N) {
                        float sc = C0F * accS[t][m][i] + bc;
                        out[(size_t)n * DIM_Hc + col] = sc / (1.f + __expf(-sc));
                    }
                }
            }
            // gate -> sigmoid in registers (gate col wave*16+l15 == vec u-tile col)
            float sgr[2][4];
            #pragma unroll
            for (int m = 0; m < 2; ++m)
            #pragma unroll
            for (int i = 0; i < 4; ++i) sgr[m][i] = 1.f / (1.f + __expf(-C0F * accS[2][m][i]));

            // ---- vec GEMMs: a1 (xs, K=256) + v2_k (xv planes, K=128 x3) ----
            f32x4 accA[2], accV[3][2];
            accA[0] = (f32x4){0,0,0,0}; accA[1] = (f32x4){0,0,0,0};
            #pragma unroll
            for (int k = 0; k < 3; ++k) { accV[k][0] = (f32x4){0,0,0,0}; accV[k][1] = (f32x4){0,0,0,0}; }

            #pragma unroll
            for (int ks = 0; ks < 8; ++ks) {
                int kf = ks * 32 + lkb;
                short8 a0 = *(const short8*)(fbr + ((l15 * 1536 + kf * 2) ^ swzr));
                short8 a1 = *(const short8*)(fbr + (((16 + l15) * 1536 + kf * 2) ^ swzr));
                short8 b = *(const short8*)(WTsv + (wave * 16 + l15) * 256 + ks * 32 + lkb);
                accA[0] = MFMA(a0, b, accA[0]);
                accA[1] = MFMA(a1, b, accA[1]);
            }
            #pragma unroll
            for (int ks = 0; ks < 4; ++ks) {
                short8 b = *(const short8*)(WTvs + (wave * 16 + l15) * 128 + ks * 32 + lkb);
                #pragma unroll
                for (int p = 0; p < 3; ++p) {
                    int kf = 384 + 128 * p + ks * 32 + lkb;
                    short8 a0 = *(const short8*)(fbr + ((l15 * 1536 + kf * 2) ^ swzr));
                    short8 a1 = *(const short8*)(fbr + (((16 + l15) * 1536 + kf * 2) ^ swzr));
                    accV[p][0] = MFMA(a0, b, accV[p][0]);
                    accV[p][1] = MFMA(a1, b, accV[p][1]);
                }
            }

            // vec epilogue: vec = C0*(a1*pv + v2*ps) * sigmoid(gate)
            {
                int u = wave * 16 + l15;
                #pragma unroll
                for (int m = 0; m < 2; ++m)
                #pragma unroll
                for (int i = 0; i < 4; ++i) {
                    int nl = m * 16 + rbase + i;
                    int n = n0 + nl;
                    if (n >= N) continue;
                    float sg  = sgr[m][i];
                    float ps  = pss[m][i];
                    float pv0 = pvv[nl * 4 + 1], pv1 = pvv[nl * 4 + 2], pv2 = pvv[nl * 4 + 3];
                    float av = accA[m][i];
                    size_t ob = (size_t)n * DIM_Hc + MUL_Sc + 3 * u;
                    out[ob + 0] = C0F * (av * pv0 + accV[0][m][i] * ps) * sg;
                    out[ob + 1] = C0F * (av * pv1 + accV[1][m][i] * ps) * sg;
                    out[ob + 2] = C0F * (av * pv2 + accV[2][m][i] * ps) * sg;
                }
            }
        }

        // ================= convert next tile into feat[cur^1], then barrier =================
        if (nx < ntiles) {
            asm volatile("s_waitcnt vmcnt(0)" ::: "memory");   // staging loads landed during compute
            convertw(cur ^ 1);
            asm volatile("s_waitcnt lgkmcnt(0)" ::: "memory"); // ds_writes complete
            __builtin_amdgcn_sched_barrier(0);
            asm volatile("s_barrier" ::: "memory");            // NO vmcnt drain
            __builtin_amdgcn_sched_barrier(0);
            cur ^= 1;
        }
    }
}

extern "C" void kernel_launch(void* const* d_in, const int* in_sizes, int n_in,
                              void* d_out, int out_size, void* d_ws, size_t ws_size,
                              hipStream_t stream) {
    const float* din  = (const float*)d_in[0];
    const float* Wss  = (const float*)d_in[1];
    const float* Wvv  = (const float*)d_in[2];
    const float* Wssg = (const float*)d_in[3];
    const float* Wvvg = (const float*)d_in[4];
    const float* Wsv  = (const float*)d_in[5];
    const float* Wvs  = (const float*)d_in[6];
    const float* bias = (const float*)d_in[7];
    float* out = (float*)d_out;
    unsigned short* wt = (unsigned short*)d_ws;

    const size_t WT_BYTES = (size_t)(384 * 384 + 128 * 256 + 128 * 128) * 2;
    if (ws_size < WT_BYTES) return;

    int N = in_sizes[0] / IN_COLS;
    int ntiles = (N + NT - 1) / NT;

    int prep_total = 384 * 384 + 128 * 256 + 128 * 128;
    prep_weights<<<(prep_total + 255) / 256, 256, 0, stream>>>(Wss, Wvv, Wssg, Wvvg, Wsv, Wvs, wt);

    fused_main<<<GRIDB, 512, 0, stream>>>(din, wt, bias, out, N, ntiles);
}

// Round 14
// 331.005 us; speedup vs baseline: 1.3579x; 1.3579x over previous
//
#include <hip/hip_runtime.h>
#include <hip/hip_bf16.h>

#define MUL_Sc 256
#define DIM_Hc 640
#define IN_COLS 644
#define KF 768
#define NTS 32

#define C0F 0.05103103630798287f
#define INV_SQRT3F 0.57735026918962576f

typedef __attribute__((ext_vector_type(8))) short short8;
typedef __attribute__((ext_vector_type(4))) float f32x4;

#define MFMA(a, b, c) __builtin_amdgcn_mfma_f32_16x16x32_bf16((a), (b), (c), 0, 0, 0)

__device__ __forceinline__ unsigned short f2bf(float x) {
    union { float f; unsigned u; } v; v.f = x;
    unsigned r = v.u + 0x7fffu + ((v.u >> 16) & 1u);   // RNE
    return (unsigned short)(r >> 16);
}

__device__ __forceinline__ void gload_lds16(const unsigned short* g, unsigned short* l) {
    __builtin_amdgcn_global_load_lds((const __attribute__((address_space(1))) void*)g,
                                     (__attribute__((address_space(3))) void*)l, 16, 0, 0);
}

// ---- weight prep: fp32 [k][col] -> bf16 transposed [col][k] ----
__global__ void prep_weights(const float* __restrict__ Wss, const float* __restrict__ Wvv,
                             const float* __restrict__ Wssg, const float* __restrict__ Wvvg,
                             const float* __restrict__ Wsv, const float* __restrict__ Wvs,
                             unsigned short* __restrict__ wt) {
    int i = blockIdx.x * 256 + threadIdx.x;
    const int N_SG = 384 * 384;
    const int N_SV = 128 * 256;
    const int N_VS = 128 * 128;
    if (i < N_SG) {
        int col = i / 384, k = i % 384;
        float v;
        if (col < 256) v = (k < 256) ? Wss[k * 256 + col] : Wvv[(k - 256) * 256 + col];
        else { int c = col - 256; v = (k < 256) ? Wssg[k * 128 + c] : Wvvg[(k - 256) * 128 + c]; }
        wt[i] = f2bf(v);
    } else if (i < N_SG + N_SV) {
        int j = i - N_SG; int col = j >> 8, k = j & 255;
        wt[i] = f2bf(Wsv[k * 128 + col]);
    } else if (i < N_SG + N_SV + N_VS) {
        int j = i - N_SG - N_SV; int col = j >> 7, k = j & 127;
        wt[i] = f2bf(Wvs[k * 128 + col]);
    }
}

// ==== kernel 1: din -> pre-swizzled bf16 feature tiles + psv (R5-verbatim math) ====
// tile T holds nodes T*32..T*32+31; tile image = exact 48KB LDS byte image k2 wants.
__global__ __launch_bounds__(512, 2)
void convert_feat(const float* __restrict__ din, unsigned short* __restrict__ featg,
                  float* __restrict__ psvg, int N) {
    const int T = blockIdx.x;
    const int tid = threadIdx.x;
    const int g = tid >> 4;       // local node 0..31
    const int j = tid & 15;       // 16 threads per node
    int n = T * NTS + g; if (n >= N) n = N - 1;
    const float* row = din + (size_t)n * IN_COLS;
    float ps  = row[DIM_Hc];
    float pv0 = row[DIM_Hc + 1], pv1 = row[DIM_Hc + 2], pv2 = row[DIM_Hc + 3];
    if (j == 0 && T * NTS + g < N) {
        float4 pp; pp.x = ps; pp.y = pv0; pp.z = pv1; pp.w = pv2;
        *(float4*)(psvg + 4 * (size_t)(T * NTS + g)) = pp;
    }
    char* fb = (char*)featg + (size_t)T * (NTS * KF * 2);
    const int swz  = (g & 7) << 4;
    const int rowb = g * (KF * 2);

    // xs: 16 consecutive elems -> 2x 16B writes
    {
        int c = 16 * j;
        float4 x0 = *(const float4*)(row + c);
        float4 x1 = *(const float4*)(row + c + 4);
        float4 x2 = *(const float4*)(row + c + 8);
        float4 x3 = *(const float4*)(row + c + 12);
        short8 p0, p1;
        p0[0]=(short)f2bf(x0.x); p0[1]=(short)f2bf(x0.y); p0[2]=(short)f2bf(x0.z); p0[3]=(short)f2bf(x0.w);
        p0[4]=(short)f2bf(x1.x); p0[5]=(short)f2bf(x1.y); p0[6]=(short)f2bf(x1.z); p0[7]=(short)f2bf(x1.w);
        p1[0]=(short)f2bf(x2.x); p1[1]=(short)f2bf(x2.y); p1[2]=(short)f2bf(x2.z); p1[3]=(short)f2bf(x2.w);
        p1[4]=(short)f2bf(x3.x); p1[5]=(short)f2bf(x3.y); p1[6]=(short)f2bf(x3.z); p1[7]=(short)f2bf(x3.w);
        *(short8*)(fb + ((rowb + c * 2) ^ swz))       = p0;
        *(short8*)(fb + ((rowb + (c + 8) * 2) ^ swz)) = p1;
    }
    // xv: 8 consecutive u -> dot + 3 k-planes
    {
        int u0 = 8 * j;
        const float* p = row + MUL_Sc + 3 * u0;
        float e[24];
        #pragma unroll
        for (int q = 0; q < 6; ++q) {
            float4 v = *(const float4*)(p + 4 * q);
            e[4*q+0] = v.x; e[4*q+1] = v.y; e[4*q+2] = v.z; e[4*q+3] = v.w;
        }
        short8 dp, k0, k1, k2;
        #pragma unroll
        for (int m = 0; m < 8; ++m) {
            float a = e[3*m], b = e[3*m+1], c = e[3*m+2];
            dp[m] = (short)f2bf((a * pv0 + b * pv1 + c * pv2) * INV_SQRT3F);
            k0[m] = (short)f2bf(a);
            k1[m] = (short)f2bf(b);
            k2[m] = (short)f2bf(c);
        }
        *(short8*)(fb + ((rowb + (256 + u0) * 2) ^ swz)) = dp;
        *(short8*)(fb + ((rowb + (384 + u0) * 2) ^ swz)) = k0;
        *(short8*)(fb + ((rowb + (512 + u0) * 2) ^ swz)) = k1;
        *(short8*)(fb + ((rowb + (640 + u0) * 2) ^ swz)) = k2;
    }
}

// ==== kernel 2: DMA-stage tile -> LDS, one barrier, R5-verified compute core ====
__global__ __launch_bounds__(512, 2)
void gemm_main(const unsigned short* __restrict__ featg, const float* __restrict__ psvg,
               const unsigned short* __restrict__ wt, const float* __restrict__ bias,
               float* __restrict__ out, int N) {
    __shared__ unsigned short feat[NTS * KF];   // 48 KB (byte image incl. swizzle)

    const int tid = threadIdx.x;
    const int T = blockIdx.x;
    const int n0 = T * NTS;

    // pure-DMA staging: 6 rounds x 512 threads x 16B = 48KB linear copy
    {
        const unsigned short* gb = featg + (size_t)T * (NTS * KF);
        unsigned short* lb = feat + (tid >> 6) * 512;     // wave-uniform base (1KB/wave)
        #pragma unroll
        for (int r = 0; r < 6; ++r)
            gload_lds16(gb + ((size_t)r * 512 + tid) * 8, lb + r * 4096);
    }
    __syncthreads();

    const int wave = tid >> 6;
    const int lane = tid & 63;
    const int l15  = lane & 15;
    const int lkb  = (lane >> 4) << 3;
    const int rbase = (lane >> 4) << 2;
    const char* fbr = (const char*)feat;
    const int swzr = (l15 & 7) << 4;

    const unsigned short* WTsg = wt;
    const unsigned short* WTsv = wt + 384 * 384;
    const unsigned short* WTvs = wt + 384 * 384 + 128 * 256;

    float pss[2][4];
    #pragma unroll
    for (int m = 0; m < 2; ++m)
    #pragma unroll
    for (int i = 0; i < 4; ++i) {
        int n = n0 + m * 16 + rbase + i;
        pss[m][i] = psvg[4 * (size_t)(n < N ? n : N - 1)];
    }

    // ---- sg GEMM: t=0,1 scal col-tiles, t=2 gate col-tile ----
    f32x4 accS[3][2];
    #pragma unroll
    for (int t = 0; t < 3; ++t) { accS[t][0] = (f32x4){0,0,0,0}; accS[t][1] = (f32x4){0,0,0,0}; }

    #pragma unroll
    for (int ks = 0; ks < 8; ++ks) {      // xs part K=256
        int kf = ks * 32 + lkb;
        short8 a0 = *(const short8*)(fbr + ((l15 * 1536 + kf * 2) ^ swzr));
        short8 a1 = *(const short8*)(fbr + (((16 + l15) * 1536 + kf * 2) ^ swzr));
        #pragma unroll
        for (int t = 0; t < 3; ++t) {
            int ct = wave + t * 8;        // t=2 -> gate cols 256+wave*16
            short8 b = *(const short8*)(WTsg + (ct * 16 + l15) * 384 + ks * 32 + lkb);
            accS[t][0] = MFMA(a0, b, accS[t][0]);
            accS[t][1] = MFMA(a1, b, accS[t][1]);
        }
    }
    #pragma unroll
    for (int t = 0; t < 3; ++t)
    #pragma unroll
    for (int m = 0; m < 2; ++m)
    #pragma unroll
    for (int i = 0; i < 4; ++i) accS[t][m][i] *= pss[m][i];
    #pragma unroll
    for (int ks = 0; ks < 4; ++ks) {      // dot part K=128
        int kf = 256 + ks * 32 + lkb;
        short8 a0 = *(const short8*)(fbr + ((l15 * 1536 + kf * 2) ^ swzr));
        short8 a1 = *(const short8*)(fbr + (((16 + l15) * 1536 + kf * 2) ^ swzr));
        #pragma unroll
        for (int t = 0; t < 3; ++t) {
            int ct = wave + t * 8;
            short8 b = *(const short8*)(WTsg + (ct * 16 + l15) * 384 + 256 + ks * 32 + lkb);
            accS[t][0] = MFMA(a0, b, accS[t][0]);
            accS[t][1] = MFMA(a1, b, accS[t][1]);
        }
    }

    // scal epilogue: silu -> global
    #pragma unroll
    for (int t = 0; t < 2; ++t) {
        int col = (wave + t * 8) * 16 + l15;
        float bc = bias[col];
        #pragma unroll
        for (int m = 0; m < 2; ++m)
        #pragma unroll
        for (int i = 0; i < 4; ++i) {
            int n = n0 + m * 16 + rbase + i;
            if (n < N) {
                float sc = C0F * accS[t][m][i] + bc;
                out[(size_t)n * DIM_Hc + col] = sc / (1.f + __expf(-sc));
            }
        }
    }
    // gate -> sigmoid in registers (gate col wave*16+l15 == vec u-tile col)
    float sgr[2][4];
    #pragma unroll
    for (int m = 0; m < 2; ++m)
    #pragma unroll
    for (int i = 0; i < 4; ++i) sgr[m][i] = 1.f / (1.f + __expf(-C0F * accS[2][m][i]));

    // ---- vec GEMMs: a1 (xs, K=256) + v2_k (xv planes, K=128 x3) ----
    f32x4 accA[2], accV[3][2];
    accA[0] = (f32x4){0,0,0,0}; accA[1] = (f32x4){0,0,0,0};
    #pragma unroll
    for (int k = 0; k < 3; ++k) { accV[k][0] = (f32x4){0,0,0,0}; accV[k][1] = (f32x4){0,0,0,0}; }

    #pragma unroll
    for (int ks = 0; ks < 8; ++ks) {
        int kf = ks * 32 + lkb;
        short8 a0 = *(const short8*)(fbr + ((l15 * 1536 + kf * 2) ^ swzr));
        short8 a1 = *(const short8*)(fbr + (((16 + l15) * 1536 + kf * 2) ^ swzr));
        short8 b = *(const short8*)(WTsv + (wave * 16 + l15) * 256 + ks * 32 + lkb);
        accA[0] = MFMA(a0, b, accA[0]);
        accA[1] = MFMA(a1, b, accA[1]);
    }
    #pragma unroll
    for (int ks = 0; ks < 4; ++ks) {
        short8 b = *(const short8*)(WTvs + (wave * 16 + l15) * 128 + ks * 32 + lkb);
        #pragma unroll
        for (int p = 0; p < 3; ++p) {
            int kf = 384 + 128 * p + ks * 32 + lkb;
            short8 a0 = *(const short8*)(fbr + ((l15 * 1536 + kf * 2) ^ swzr));
            short8 a1 = *(const short8*)(fbr + (((16 + l15) * 1536 + kf * 2) ^ swzr));
            accV[p][0] = MFMA(a0, b, accV[p][0]);
            accV[p][1] = MFMA(a1, b, accV[p][1]);
        }
    }

    // vec epilogue: vec = C0*(a1*pv + v2*ps) * sigmoid(gate)
    {
        int u = wave * 16 + l15;
        #pragma unroll
        for (int m = 0; m < 2; ++m)
        #pragma unroll
        for (int i = 0; i < 4; ++i) {
            int nl = m * 16 + rbase + i;
            int n = n0 + nl;
            if (n >= N) continue;
            float sg  = sgr[m][i];
            float ps  = pss[m][i];
            float pv0 = psvg[4 * (size_t)n + 1];
            float pv1 = psvg[4 * (size_t)n + 2];
            float pv2 = psvg[4 * (size_t)n + 3];
            float av = accA[m][i];
            size_t ob = (size_t)n * DIM_Hc + MUL_Sc + 3 * u;
            out[ob + 0] = C0F * (av * pv0 + accV[0][m][i] * ps) * sg;
            out[ob + 1] = C0F * (av * pv1 + accV[1][m][i] * ps) * sg;
            out[ob + 2] = C0F * (av * pv2 + accV[2][m][i] * ps) * sg;
        }
    }
}

// ==== fallback: R12 fused kernel (NT=64, single barrier) — used if ws too small ====
__global__ __launch_bounds__(512, 2)
void fused_fallback(const float* __restrict__ din, const unsigned short* __restrict__ wt,
                    const float* __restrict__ bias, float* __restrict__ out, int N) {
    __shared__ unsigned short feat[64 * KF];
    __shared__ float psv[64 * 4];

    const int tid = threadIdx.x;
    const int n0 = blockIdx.x * 64;
    {
        const int g = tid >> 3;
        const int j = tid & 7;
        int n = n0 + g; if (n >= N) n = N - 1;
        const float* row = din + (size_t)n * IN_COLS;
        float ps  = row[DIM_Hc];
        float pv0 = row[DIM_Hc + 1], pv1 = row[DIM_Hc + 2], pv2 = row[DIM_Hc + 3];
        if (j == 0) { psv[g*4+0] = ps; psv[g*4+1] = pv0; psv[g*4+2] = pv1; psv[g*4+3] = pv2; }
        char* fb = (char*)feat;
        const int swz  = (g & 7) << 4;
        const int rowb = g * (KF * 2);
        #pragma unroll
        for (int half = 0; half < 2; ++half) {
            int c = 32 * j + 16 * half;
            float4 x0 = *(const float4*)(row + c);
            float4 x1 = *(const float4*)(row + c + 4);
            float4 x2 = *(const float4*)(row + c + 8);
            float4 x3 = *(const float4*)(row + c + 12);
            short8 p0, p1;
            p0[0]=(short)f2bf(x0.x); p0[1]=(short)f2bf(x0.y); p0[2]=(short)f2bf(x0.z); p0[3]=(short)f2bf(x0.w);
            p0[4]=(short)f2bf(x1.x); p0[5]=(short)f2bf(x1.y); p0[6]=(short)f2bf(x1.z); p0[7]=(short)f2bf(x1.w);
            p1[0]=(short)f2bf(x2.x); p1[1]=(short)f2bf(x2.y); p1[2]=(short)f2bf(x2.z); p1[3]=(short)f2bf(x2.w);
            p1[4]=(short)f2bf(x3.x); p1[5]=(short)f2bf(x3.y); p1[6]=(short)f2bf(x3.z); p1[7]=(short)f2bf(x3.w);
            *(short8*)(fb + ((rowb + c * 2) ^ swz))       = p0;
            *(short8*)(fb + ((rowb + (c + 8) * 2) ^ swz)) = p1;
        }
        #pragma unroll
        for (int half = 0; half < 2; ++half) {
            int u0 = 16 * j + 8 * half;
            const float* p = row + MUL_Sc + 3 * u0;
            float e[24];
            #pragma unroll
            for (int q = 0; q < 6; ++q) {
                float4 v = *(const float4*)(p + 4 * q);
                e[4*q+0] = v.x; e[4*q+1] = v.y; e[4*q+2] = v.z; e[4*q+3] = v.w;
            }
            short8 dp, k0, k1, k2;
            #pragma unroll
            for (int m = 0; m < 8; ++m) {
                float a = e[3*m], b = e[3*m+1], c = e[3*m+2];
                dp[m] = (short)f2bf((a * pv0 + b * pv1 + c * pv2) * INV_SQRT3F);
                k0[m] = (short)f2bf(a); k1[m] = (short)f2bf(b); k2[m] = (short)f2bf(c);
            }
            *(short8*)(fb + ((rowb + (256 + u0) * 2) ^ swz)) = dp;
            *(short8*)(fb + ((rowb + (384 + u0) * 2) ^ swz)) = k0;
            *(short8*)(fb + ((rowb + (512 + u0) * 2) ^ swz)) = k1;
            *(short8*)(fb + ((rowb + (640 + u0) * 2) ^ swz)) = k2;
        }
    }
    __syncthreads();

    const int wave = tid >> 6;
    const int lane = tid & 63;
    const int l15  = lane & 15;
    const int lkb  = (lane >> 4) << 3;
    const int rbase = (lane >> 4) << 2;
    const char* fbr = (const char*)feat;
    const int swzr = (l15 & 7) << 4;

    const unsigned short* WTsg = wt;
    const unsigned short* WTsv = wt + 384 * 384;
    const unsigned short* WTvs = wt + 384 * 384 + 128 * 256;

    float pss[4][4];
    #pragma unroll
    for (int m = 0; m < 4; ++m)
    #pragma unroll
    for (int i = 0; i < 4; ++i) pss[m][i] = psv[(m * 16 + rbase + i) * 4];

    f32x4 accS[3][4];
    #pragma unroll
    for (int t = 0; t < 3; ++t)
    #pragma unroll
    for (int m = 0; m < 4; ++m) accS[t][m] = (f32x4){0,0,0,0};

    #pragma unroll
    for (int ks = 0; ks < 8; ++ks) {
        int kf = ks * 32 + lkb;
        short8 a[4];
        #pragma unroll
        for (int m = 0; m < 4; ++m)
            a[m] = *(const short8*)(fbr + (((m * 16 + l15) * 1536 + kf * 2) ^ swzr));
        #pragma unroll
        for (int t = 0; t < 3; ++t) {
            int ct = wave + t * 8;
            short8 b = *(const short8*)(WTsg + (ct * 16 + l15) * 384 + ks * 32 + lkb);
            #pragma unroll
            for (int m = 0; m < 4; ++m) accS[t][m] = MFMA(a[m], b, accS[t][m]);
        }
    }
    #pragma unroll
    for (int t = 0; t < 3; ++t)
    #pragma unroll
    for (int m = 0; m < 4; ++m)
    #pragma unroll
    for (int i = 0; i < 4; ++i) accS[t][m][i] *= pss[m][i];
    #pragma unroll
    for (int ks = 0; ks < 4; ++ks) {
        int kf = 256 + ks * 32 + lkb;
        short8 a[4];
        #pragma unroll
        for (int m = 0; m < 4; ++m)
            a[m] = *(const short8*)(fbr + (((m * 16 + l15) * 1536 + kf * 2) ^ swzr));
        #pragma unroll
        for (int t = 0; t < 3; ++t) {
            int ct = wave + t * 8;
            short8 b = *(const short8*)(WTsg + (ct * 16 + l15) * 384 + 256 + ks * 32 + lkb);
            #pragma unroll
            for (int m = 0; m < 4; ++m) accS[t][m] = MFMA(a[m], b, accS[t][m]);
        }
    }
    #pragma unroll
    for (int t = 0; t < 2; ++t) {
        int col = (wave + t * 8) * 16 + l15;
        float bc = bias[col];
        #pragma unroll
        for (int m = 0; m < 4; ++m)
        #pragma unroll
        for (int i = 0; i < 4; ++i) {
            int n = n0 + m * 16 + rbase + i;
            if (n < N) {
                float sc = C0F * accS[t][m][i] + bc;
                out[(size_t)n * DIM_Hc + col] = sc / (1.f + __expf(-sc));
            }
        }
    }
    float sgr[4][4];
    #pragma unroll
    for (int m = 0; m < 4; ++m)
    #pragma unroll
    for (int i = 0; i < 4; ++i) sgr[m][i] = 1.f / (1.f + __expf(-C0F * accS[2][m][i]));

    f32x4 accA[4], accV[3][4];
    #pragma unroll
    for (int m = 0; m < 4; ++m) accA[m] = (f32x4){0,0,0,0};
    #pragma unroll
    for (int k = 0; k < 3; ++k)
    #pragma unroll
    for (int m = 0; m < 4; ++m) accV[k][m] = (f32x4){0,0,0,0};

    #pragma unroll
    for (int ks = 0; ks < 8; ++ks) {
        int kf = ks * 32 + lkb;
        short8 b = *(const short8*)(WTsv + (wave * 16 + l15) * 256 + ks * 32 + lkb);
        #pragma unroll
        for (int m = 0; m < 4; ++m) {
            short8 a = *(const short8*)(fbr + (((m * 16 + l15) * 1536 + kf * 2) ^ swzr));
            accA[m] = MFMA(a, b, accA[m]);
        }
    }
    #pragma unroll
    for (int ks = 0; ks < 4; ++ks) {
        short8 b = *(const short8*)(WTvs + (wave * 16 + l15) * 128 + ks * 32 + lkb);
        #pragma unroll
        for (int p = 0; p < 3; ++p) {
            int kf = 384 + 128 * p + ks * 32 + lkb;
            #pragma unroll
            for (int m = 0; m < 4; ++m) {
                short8 a = *(const short8*)(fbr + (((m * 16 + l15) * 1536 + kf * 2) ^ swzr));
                accV[p][m] = MFMA(a, b, accV[p][m]);
            }
        }
    }
    {
        int u = wave * 16 + l15;
        #pragma unroll
        for (int m = 0; m < 4; ++m)
        #pragma unroll
        for (int i = 0; i < 4; ++i) {
            int nl = m * 16 + rbase + i;
            int n = n0 + nl;
            if (n >= N) continue;
            float sg  = sgr[m][i];
            float ps  = pss[m][i];
            float pv0 = psv[nl * 4 + 1], pv1 = psv[nl * 4 + 2], pv2 = psv[nl * 4 + 3];
            float av = accA[m][i];
            size_t ob = (size_t)n * DIM_Hc + MUL_Sc + 3 * u;
            out[ob + 0] = C0F * (av * pv0 + accV[0][m][i] * ps) * sg;
            out[ob + 1] = C0F * (av * pv1 + accV[1][m][i] * ps) * sg;
            out[ob + 2] = C0F * (av * pv2 + accV[2][m][i] * ps) * sg;
        }
    }
}

extern "C" void kernel_launch(void* const* d_in, const int* in_sizes, int n_in,
                              void* d_out, int out_size, void* d_ws, size_t ws_size,
                              hipStream_t stream) {
    const float* din  = (const float*)d_in[0];
    const float* Wss  = (const float*)d_in[1];
    const float* Wvv  = (const float*)d_in[2];
    const float* Wssg = (const float*)d_in[3];
    const float* Wvvg = (const float*)d_in[4];
    const float* Wsv  = (const float*)d_in[5];
    const float* Wvs  = (const float*)d_in[6];
    const float* bias = (const float*)d_in[7];
    float* out = (float*)d_out;
    unsigned short* wt = (unsigned short*)d_ws;

    const size_t WT_SHORTS = 384 * 384 + 128 * 256 + 128 * 128;
    const size_t WT_BYTES = WT_SHORTS * 2;
    if (ws_size < WT_BYTES) return;

    int N = in_sizes[0] / IN_COLS;
    int ntiles = (N + NTS - 1) / NTS;

    int prep_total = (int)WT_SHORTS;
    prep_weights<<<(prep_total + 255) / 256, 256, 0, stream>>>(Wss, Wvv, Wssg, Wvvg, Wsv, Wvs, wt);

    size_t feat_bytes = (size_t)ntiles * NTS * KF * 2;
    size_t psv_bytes  = (size_t)ntiles * NTS * 4 * sizeof(float);
    size_t need = WT_BYTES + feat_bytes + psv_bytes;

    if (ws_size >= need) {
        unsigned short* featg = wt + WT_SHORTS;
        float* psvg = (float*)((char*)d_ws + WT_BYTES + feat_bytes);
        convert_feat<<<ntiles, 512, 0, stream>>>(din, featg, psvg, N);
        gemm_main<<<ntiles, 512, 0, stream>>>(featg, psvg, wt, bias, out, N);
    } else {
        int nblocks = (N + 63) / 64;
        fused_fallback<<<nblocks, 512, 0, stream>>>(din, wt, bias, out, N);
    }
}

// Round 15
// 314.854 us; speedup vs baseline: 1.4275x; 1.0513x over previous
//
#include <hip/hip_runtime.h>
#include <hip/hip_bf16.h>

#define MUL_Sc 256
#define DIM_Hc 640
#define IN_COLS 644
#define KF 768
#define NTS 32

#define C0F 0.05103103630798287f
#define INV_SQRT3F 0.57735026918962576f

typedef __attribute__((ext_vector_type(8))) short short8;
typedef __attribute__((ext_vector_type(4))) float f32x4;

#define MFMA(a, b, c) __builtin_amdgcn_mfma_f32_16x16x32_bf16((a), (b), (c), 0, 0, 0)

__device__ __forceinline__ unsigned short f2bf(float x) {
    union { float f; unsigned u; } v; v.f = x;
    unsigned r = v.u + 0x7fffu + ((v.u >> 16) & 1u);   // RNE
    return (unsigned short)(r >> 16);
}

__device__ __forceinline__ void gload_lds16(const unsigned short* g, unsigned short* l) {
    __builtin_amdgcn_global_load_lds((const __attribute__((address_space(1))) void*)g,
                                     (__attribute__((address_space(3))) void*)l, 16, 0, 0);
}

// ---- weight prep: fp32 [k][col] -> bf16 transposed [col][k] ----
__global__ void prep_weights(const float* __restrict__ Wss, const float* __restrict__ Wvv,
                             const float* __restrict__ Wssg, const float* __restrict__ Wvvg,
                             const float* __restrict__ Wsv, const float* __restrict__ Wvs,
                             unsigned short* __restrict__ wt) {
    int i = blockIdx.x * 256 + threadIdx.x;
    const int N_SG = 384 * 384;
    const int N_SV = 128 * 256;
    const int N_VS = 128 * 128;
    if (i < N_SG) {
        int col = i / 384, k = i % 384;
        float v;
        if (col < 256) v = (k < 256) ? Wss[k * 256 + col] : Wvv[(k - 256) * 256 + col];
        else { int c = col - 256; v = (k < 256) ? Wssg[k * 128 + c] : Wvvg[(k - 256) * 128 + c]; }
        wt[i] = f2bf(v);
    } else if (i < N_SG + N_SV) {
        int j = i - N_SG; int col = j >> 8, k = j & 255;
        wt[i] = f2bf(Wsv[k * 128 + col]);
    } else if (i < N_SG + N_SV + N_VS) {
        int j = i - N_SG - N_SV; int col = j >> 7, k = j & 127;
        wt[i] = f2bf(Wvs[k * 128 + col]);
    }
}

// ==== kernel 1: din -> pre-swizzled bf16 feature tiles + psv (unchanged, benched) ====
__global__ __launch_bounds__(512, 2)
void convert_feat(const float* __restrict__ din, unsigned short* __restrict__ featg,
                  float* __restrict__ psvg, int N) {
    const int T = blockIdx.x;
    const int tid = threadIdx.x;
    const int g = tid >> 4;
    const int j = tid & 15;
    int n = T * NTS + g; if (n >= N) n = N - 1;
    const float* row = din + (size_t)n * IN_COLS;
    float ps  = row[DIM_Hc];
    float pv0 = row[DIM_Hc + 1], pv1 = row[DIM_Hc + 2], pv2 = row[DIM_Hc + 3];
    if (j == 0 && T * NTS + g < N) {
        float4 pp; pp.x = ps; pp.y = pv0; pp.z = pv1; pp.w = pv2;
        *(float4*)(psvg + 4 * (size_t)(T * NTS + g)) = pp;
    }
    char* fb = (char*)featg + (size_t)T * (NTS * KF * 2);
    const int swz  = (g & 7) << 4;
    const int rowb = g * (KF * 2);
    {
        int c = 16 * j;
        float4 x0 = *(const float4*)(row + c);
        float4 x1 = *(const float4*)(row + c + 4);
        float4 x2 = *(const float4*)(row + c + 8);
        float4 x3 = *(const float4*)(row + c + 12);
        short8 p0, p1;
        p0[0]=(short)f2bf(x0.x); p0[1]=(short)f2bf(x0.y); p0[2]=(short)f2bf(x0.z); p0[3]=(short)f2bf(x0.w);
        p0[4]=(short)f2bf(x1.x); p0[5]=(short)f2bf(x1.y); p0[6]=(short)f2bf(x1.z); p0[7]=(short)f2bf(x1.w);
        p1[0]=(short)f2bf(x2.x); p1[1]=(short)f2bf(x2.y); p1[2]=(short)f2bf(x2.z); p1[3]=(short)f2bf(x2.w);
        p1[4]=(short)f2bf(x3.x); p1[5]=(short)f2bf(x3.y); p1[6]=(short)f2bf(x3.z); p1[7]=(short)f2bf(x3.w);
        *(short8*)(fb + ((rowb + c * 2) ^ swz))       = p0;
        *(short8*)(fb + ((rowb + (c + 8) * 2) ^ swz)) = p1;
    }
    {
        int u0 = 8 * j;
        const float* p = row + MUL_Sc + 3 * u0;
        float e[24];
        #pragma unroll
        for (int q = 0; q < 6; ++q) {
            float4 v = *(const float4*)(p + 4 * q);
            e[4*q+0] = v.x; e[4*q+1] = v.y; e[4*q+2] = v.z; e[4*q+3] = v.w;
        }
        short8 dp, k0, k1, k2;
        #pragma unroll
        for (int m = 0; m < 8; ++m) {
            float a = e[3*m], b = e[3*m+1], c = e[3*m+2];
            dp[m] = (short)f2bf((a * pv0 + b * pv1 + c * pv2) * INV_SQRT3F);
            k0[m] = (short)f2bf(a);
            k1[m] = (short)f2bf(b);
            k2[m] = (short)f2bf(c);
        }
        *(short8*)(fb + ((rowb + (256 + u0) * 2) ^ swz)) = dp;
        *(short8*)(fb + ((rowb + (384 + u0) * 2) ^ swz)) = k0;
        *(short8*)(fb + ((rowb + (512 + u0) * 2) ^ swz)) = k1;
        *(short8*)(fb + ((rowb + (640 + u0) * 2) ^ swz)) = k2;
    }
}

// ==== kernel 2: DMA-stage tile -> LDS, compute, COALESCED stores via LDS bounce ====
__global__ __launch_bounds__(512, 2)
void gemm_main(const unsigned short* __restrict__ featg, const float* __restrict__ psvg,
               const unsigned short* __restrict__ wt, const float* __restrict__ bias,
               float* __restrict__ out, int N) {
    __shared__ unsigned short feat[NTS * KF];   // 48 KB; reused as f32 bounce [16][644] in epilogue

    const int tid = threadIdx.x;
    const int T = blockIdx.x;
    const int n0 = T * NTS;

    // pure-DMA staging: 6 rounds x 512 threads x 16B = 48KB linear copy
    {
        const unsigned short* gb = featg + (size_t)T * (NTS * KF);
        unsigned short* lb = feat + (tid >> 6) * 512;
        #pragma unroll
        for (int r = 0; r < 6; ++r)
            gload_lds16(gb + ((size_t)r * 512 + tid) * 8, lb + r * 4096);
    }
    __syncthreads();

    const int wave = tid >> 6;
    const int lane = tid & 63;
    const int l15  = lane & 15;
    const int lkb  = (lane >> 4) << 3;
    const int rbase = (lane >> 4) << 2;
    const char* fbr = (const char*)feat;
    const int swzr = (l15 & 7) << 4;

    const unsigned short* WTsg = wt;
    const unsigned short* WTsv = wt + 384 * 384;
    const unsigned short* WTvs = wt + 384 * 384 + 128 * 256;

    float bc0 = bias[(wave)     * 16 + l15];
    float bc1 = bias[(wave + 8) * 16 + l15];

    float pss[2][4];
    #pragma unroll
    for (int m = 0; m < 2; ++m)
    #pragma unroll
    for (int i = 0; i < 4; ++i) {
        int n = n0 + m * 16 + rbase + i;
        pss[m][i] = psvg[4 * (size_t)(n < N ? n : N - 1)];
    }

    // ---- sg GEMM: t=0,1 scal col-tiles, t=2 gate col-tile ----
    f32x4 accS[3][2];
    #pragma unroll
    for (int t = 0; t < 3; ++t) { accS[t][0] = (f32x4){0,0,0,0}; accS[t][1] = (f32x4){0,0,0,0}; }

    #pragma unroll
    for (int ks = 0; ks < 8; ++ks) {      // xs part K=256
        int kf = ks * 32 + lkb;
        short8 a0 = *(const short8*)(fbr + ((l15 * 1536 + kf * 2) ^ swzr));
        short8 a1 = *(const short8*)(fbr + (((16 + l15) * 1536 + kf * 2) ^ swzr));
        #pragma unroll
        for (int t = 0; t < 3; ++t) {
            int ct = wave + t * 8;
            short8 b = *(const short8*)(WTsg + (ct * 16 + l15) * 384 + ks * 32 + lkb);
            accS[t][0] = MFMA(a0, b, accS[t][0]);
            accS[t][1] = MFMA(a1, b, accS[t][1]);
        }
    }
    #pragma unroll
    for (int t = 0; t < 3; ++t)
    #pragma unroll
    for (int m = 0; m < 2; ++m)
    #pragma unroll
    for (int i = 0; i < 4; ++i) accS[t][m][i] *= pss[m][i];
    #pragma unroll
    for (int ks = 0; ks < 4; ++ks) {      // dot part K=128
        int kf = 256 + ks * 32 + lkb;
        short8 a0 = *(const short8*)(fbr + ((l15 * 1536 + kf * 2) ^ swzr));
        short8 a1 = *(const short8*)(fbr + (((16 + l15) * 1536 + kf * 2) ^ swzr));
        #pragma unroll
        for (int t = 0; t < 3; ++t) {
            int ct = wave + t * 8;
            short8 b = *(const short8*)(WTsg + (ct * 16 + l15) * 384 + 256 + ks * 32 + lkb);
            accS[t][0] = MFMA(a0, b, accS[t][0]);
            accS[t][1] = MFMA(a1, b, accS[t][1]);
        }
    }

    // gate -> sigmoid in registers (gate col wave*16+l15 == vec u-tile col)
    float sgr[2][4];
    #pragma unroll
    for (int m = 0; m < 2; ++m)
    #pragma unroll
    for (int i = 0; i < 4; ++i) sgr[m][i] = 1.f / (1.f + __expf(-C0F * accS[2][m][i]));

    // ---- vec GEMMs: a1 (xs, K=256) + v2_k (xv planes, K=128 x3) ----
    f32x4 accA[2], accV[3][2];
    accA[0] = (f32x4){0,0,0,0}; accA[1] = (f32x4){0,0,0,0};
    #pragma unroll
    for (int k = 0; k < 3; ++k) { accV[k][0] = (f32x4){0,0,0,0}; accV[k][1] = (f32x4){0,0,0,0}; }

    #pragma unroll
    for (int ks = 0; ks < 8; ++ks) {
        int kf = ks * 32 + lkb;
        short8 a0 = *(const short8*)(fbr + ((l15 * 1536 + kf * 2) ^ swzr));
        short8 a1 = *(const short8*)(fbr + (((16 + l15) * 1536 + kf * 2) ^ swzr));
        short8 b = *(const short8*)(WTsv + (wave * 16 + l15) * 256 + ks * 32 + lkb);
        accA[0] = MFMA(a0, b, accA[0]);
        accA[1] = MFMA(a1, b, accA[1]);
    }
    #pragma unroll
    for (int ks = 0; ks < 4; ++ks) {
        short8 b = *(const short8*)(WTvs + (wave * 16 + l15) * 128 + ks * 32 + lkb);
        #pragma unroll
        for (int p = 0; p < 3; ++p) {
            int kf = 384 + 128 * p + ks * 32 + lkb;
            short8 a0 = *(const short8*)(fbr + ((l15 * 1536 + kf * 2) ^ swzr));
            short8 a1 = *(const short8*)(fbr + (((16 + l15) * 1536 + kf * 2) ^ swzr));
            accV[p][0] = MFMA(a0, b, accV[p][0]);
            accV[p][1] = MFMA(a1, b, accV[p][1]);
        }
    }

    __syncthreads();   // all feat LDS reads done -> reuse feat as f32 bounce buffer

    // ==== epilogue: LDS bounce -> fully coalesced 40KB streaming stores per half ====
    float* ldso = (float*)feat;      // [16][644] floats = 41.2 KB
    const int u = wave * 16 + l15;
    #pragma unroll
    for (int m = 0; m < 2; ++m) {
        // write phase: silu(scal) and gated vec into LDS rows 0..15 (pad stride 644)
        #pragma unroll
        for (int t = 0; t < 2; ++t) {
            int col = (wave + t * 8) * 16 + l15;
            float bc = t == 0 ? bc0 : bc1;
            #pragma unroll
            for (int i = 0; i < 4; ++i) {
                int r = rbase + i;
                float sc = C0F * accS[t][m][i] + bc;
                ldso[r * 644 + col] = sc / (1.f + __expf(-sc));
            }
        }
        #pragma unroll
        for (int i = 0; i < 4; ++i) {
            int r = rbase + i;
            int n = n0 + m * 16 + r;
            size_t pb = 4 * (size_t)(n < N ? n : N - 1);
            float ps  = pss[m][i];
            float pv0 = psvg[pb + 1], pv1 = psvg[pb + 2], pv2 = psvg[pb + 3];
            float sg  = sgr[m][i];
            float av  = accA[m][i];
            float* vb = ldso + r * 644 + MUL_Sc + 3 * u;
            vb[0] = C0F * (av * pv0 + accV[0][m][i] * ps) * sg;
            vb[1] = C0F * (av * pv1 + accV[1][m][i] * ps) * sg;
            vb[2] = C0F * (av * pv2 + accV[2][m][i] * ps) * sg;
        }
        __syncthreads();
        // read + coalesced store: 32 threads per row x 20 floats = 640 (full rows, full lines)
        {
            int r  = tid >> 5;             // 0..15
            int c0 = (tid & 31) * 20;      // 0..620
            int n  = n0 + m * 16 + r;
            if (n < N) {
                const float* src = ldso + r * 644 + c0;
                float* dst = out + (size_t)n * DIM_Hc + c0;
                #pragma unroll
                for (int q = 0; q < 5; ++q)
                    *(float4*)(dst + 4 * q) = *(const float4*)(src + 4 * q);
            }
        }
        __syncthreads();   // protect ldso before next half overwrites
    }
}

extern "C" void kernel_launch(void* const* d_in, const int* in_sizes, int n_in,
                              void* d_out, int out_size, void* d_ws, size_t ws_size,
                              hipStream_t stream) {
    const float* din  = (const float*)d_in[0];
    const float* Wss  = (const float*)d_in[1];
    const float* Wvv  = (const float*)d_in[2];
    const float* Wssg = (const float*)d_in[3];
    const float* Wvvg = (const float*)d_in[4];
    const float* Wsv  = (const float*)d_in[5];
    const float* Wvs  = (const float*)d_in[6];
    const float* bias = (const float*)d_in[7];
    float* out = (float*)d_out;
    unsigned short* wt = (unsigned short*)d_ws;

    const size_t WT_SHORTS = 384 * 384 + 128 * 256 + 128 * 128;
    const size_t WT_BYTES = WT_SHORTS * 2;
    if (ws_size < WT_BYTES) return;

    int N = in_sizes[0] / IN_COLS;
    int ntiles = (N + NTS - 1) / NTS;

    int prep_total = (int)WT_SHORTS;
    prep_weights<<<(prep_total + 255) / 256, 256, 0, stream>>>(Wss, Wvv, Wssg, Wvvg, Wsv, Wvs, wt);

    size_t feat_bytes = (size_t)ntiles * NTS * KF * 2;
    size_t psv_bytes  = (size_t)ntiles * NTS * 4 * sizeof(float);
    size_t need = WT_BYTES + feat_bytes + psv_bytes;
    if (ws_size < need) return;   // N=100000 -> ~156MB, expected to fit

    unsigned short* featg = wt + WT_SHORTS;
    float* psvg = (float*)((char*)d_ws + WT_BYTES + feat_bytes);
    convert_feat<<<ntiles, 512, 0, stream>>>(din, featg, psvg, N);
    gemm_main<<<ntiles, 512, 0, stream>>>(featg, psvg, wt, bias, out, N);
}